// Round 14
// baseline (703.452 us; speedup 1.0000x reference)
//
#include <hip/hip_runtime.h>

// ---------------------------------------------------------------------------
// MHLP predictor — R13 structure + LDS weight staging.
// R13 (658 us; k_attn 460) was uniform-weight-load latency-bound: ~1 KB of
// wave-uniform weights per inner iteration streamed from global thrashed
// K$/L1 (VALUBusy 26%, HBM 1%, ~25 cyc/inst). This round keeps R13's loop
// structure and math IDENTICAL (absmax must stay 2.441406e-3) and stages:
//   k_attn: Wq+Wk (first 32 KB of in_proj) -> LDS; Wv/opwT stay global/SMEM
//           (splits 4 uniform streams across LDS + K$ pipes, each cache-fit)
//   k_enc : W2T (32 KB) -> LDS; W1 per-lane gathers stay global (L1).
// 32 KB LDS -> 3 blocks/CU retained (VGPR 148, 12 waves/CU).
// Predict: k_attn 80-150 us, k_enc 50-80 us, total ~180-280 us.
// ---------------------------------------------------------------------------

#define BTOT 262144

// d_ws float layout:
//   [0..256)        q0t[4][64]
//   [256..512)      k0t[4][64]
//   [512..768)      u0t[4][64]    (= out_proj_w . v0(hw))
//   [768..784)      s00t[4][4]    (raw q0.k0 per head, unscaled)
//   [1024..5120)    opwT[64][64]  (opwT[n][m] = opw[m][n])
//   [8192..16384)   W2T[128][64]  (W2T[j][n]  = W2[n][j])
//   [16384..)       arT4: float4 [16][BTOT]  (LN1 output, interleaved)
#define WS_OPWT 1024
#define WS_W2T  8192
#define WS_ART  16384

// ---------------- precompute: tables + transposes --------------------------
__global__ void k_pre(const float* __restrict__ hwe,
                      const float* __restrict__ ipw, const float* __restrict__ ipb,
                      const float* __restrict__ opw, const float* __restrict__ W2,
                      float* __restrict__ ws) {
  __shared__ float sq[256], sk[256], sv[256];
  const int t = threadIdx.x;          // 256 threads: r = t>>6 (hw row), n = t&63
  const int r = t >> 6, n = t & 63;
  const float* x = hwe + r * 64;
  float q = ipb[n], k = ipb[64 + n], v = ipb[128 + n];
#pragma unroll
  for (int j = 0; j < 64; ++j) {
    q += ipw[n * 64 + j] * x[j];
    k += ipw[(64 + n) * 64 + j] * x[j];
    v += ipw[(128 + n) * 64 + j] * x[j];
  }
  sq[t] = q; sk[t] = k; sv[t] = v;
  ws[t] = q; ws[256 + t] = k;
  __syncthreads();
  float u = 0.f;
#pragma unroll
  for (int j = 0; j < 64; ++j) u += opw[n * 64 + j] * sv[r * 64 + j];
  ws[512 + t] = u;
  if (t < 16) {
    const int rr = t >> 2, h = t & 3;
    float s = 0.f;
#pragma unroll
    for (int d = 0; d < 16; ++d)
      s += sq[rr * 64 + h * 16 + d] * sk[rr * 64 + h * 16 + d];
    ws[768 + t] = s;
  }
  // opwT[n][m] = opw[m][n]
  for (int i = t; i < 4096; i += 256) {
    const int nn = i >> 6, m = i & 63;
    ws[WS_OPWT + i] = opw[m * 64 + nn];
  }
  // W2T[j][n] = W2[n][j]
  for (int i = t; i < 8192; i += 256) {
    const int j = i >> 6, nn = i & 63;
    ws[WS_W2T + i] = W2[nn * 128 + j];
  }
}

// ---------------- K1: encoder -> arT4 --------------------------------------
__global__ __launch_bounds__(256) void k_enc(
    const int* __restrict__ g_op, const int* __restrict__ g_wd,
    const float* __restrict__ g_W1,  const float* __restrict__ g_b1,
    const float* __restrict__ g_b2,
    const float* __restrict__ g_ln1g, const float* __restrict__ g_ln1b,
    const float* __restrict__ ws) {
  __shared__ float sW2T[8192];   // 32 KB
  {
    const float4* src = (const float4*)(ws + WS_W2T);
    float4* dst = (float4*)sW2T;
#pragma unroll
    for (int c = 0; c < 8; ++c)
      dst[c * 256 + threadIdx.x] = src[c * 256 + threadIdx.x];
  }
  __syncthreads();

  const int i = blockIdx.x * 256 + threadIdx.x;

  const int c0 = g_op[i * 5 + 0] * 3 + g_wd[i * 5 + 0];
  const int c1 = 15 + g_op[i * 5 + 1] * 3 + g_wd[i * 5 + 1];
  const int c2 = 30 + g_op[i * 5 + 2] * 3 + g_wd[i * 5 + 2];
  const int c3 = 45 + g_op[i * 5 + 3] * 3 + g_wd[i * 5 + 3];
  const int c4 = 60 + g_op[i * 5 + 4] * 3 + g_wd[i * 5 + 4];

  float ar[64];
#pragma unroll
  for (int n = 0; n < 64; ++n) ar[n] = g_b2[n];

#pragma unroll 2
  for (int j = 0; j < 128; ++j) {
    const float* row = g_W1 + j * 75;
    float hj = g_b1[j] + row[c0] + row[c1] + row[c2] + row[c3] + row[c4];
    hj = hj > 0.f ? hj : 0.f;
    const float* w = sW2T + j * 64;
#pragma unroll
    for (int n = 0; n < 64; ++n) ar[n] += w[n] * hj;
  }

  float mean = 0.f;
#pragma unroll
  for (int n = 0; n < 64; ++n) mean += ar[n];
  mean *= (1.f / 64.f);
  float var = 0.f;
#pragma unroll
  for (int n = 0; n < 64; ++n) { const float d = ar[n] - mean; var += d * d; }
  var *= (1.f / 64.f);
  const float rstd = rsqrtf(var + 1e-5f);
#pragma unroll
  for (int n = 0; n < 64; ++n)
    ar[n] = (ar[n] - mean) * rstd * g_ln1g[n] + g_ln1b[n];

  float4* arT4 = (float4*)(ws + WS_ART);
#pragma unroll
  for (int k = 0; k < 16; ++k) {
    float4 v;
    v.x = ar[4 * k]; v.y = ar[4 * k + 1]; v.z = ar[4 * k + 2]; v.w = ar[4 * k + 3];
    arT4[(size_t)k * BTOT + i] = v;
  }
}

// ---------------- K2: attention + head -> out ------------------------------
__global__ __launch_bounds__(256) void k_attn(
    const int* __restrict__ g_hw,
    const float* __restrict__ g_hwe,
    const float* __restrict__ g_ipw, const float* __restrict__ g_ipb,
    const float* __restrict__ g_opb,
    const float* __restrict__ g_ln2g, const float* __restrict__ g_ln2b,
    const float* __restrict__ g_W3,  const float* __restrict__ g_b3,
    const float* __restrict__ g_W4,  const float* __restrict__ g_b4,
    const float* __restrict__ ws,
    float* __restrict__ g_out) {
  __shared__ float sWqk[8192];   // 32 KB: in_proj rows 0..127 (Wq then Wk)
  {
    const float4* src = (const float4*)g_ipw;
    float4* dst = (float4*)sWqk;
#pragma unroll
    for (int c = 0; c < 8; ++c)
      dst[c * 256 + threadIdx.x] = src[c * 256 + threadIdx.x];
  }
  __syncthreads();

  const int i = blockIdx.x * 256 + threadIdx.x;
  const int hw = g_hw[i];

  float ar[64];
  const float4* arT4 = (const float4*)(ws + WS_ART);
#pragma unroll
  for (int k = 0; k < 16; ++k) {
    const float4 v = arT4[(size_t)k * BTOT + i];
    ar[4 * k] = v.x; ar[4 * k + 1] = v.y; ar[4 * k + 2] = v.z; ar[4 * k + 3] = v.w;
  }

  const float* q0r = ws + hw * 64;
  const float* k0r = ws + 256 + hw * 64;
  const float* u0r = ws + 512 + hw * 64;
  const float* opwT = ws + WS_OPWT;

  float u1[64];
#pragma unroll
  for (int m = 0; m < 64; ++m) u1[m] = 0.f;

  float s01[4], s10[4], s11[4];
#pragma unroll
  for (int h = 0; h < 4; ++h) {
    float a01 = 0.f, a10 = 0.f, a11 = 0.f;
#pragma unroll 1
    for (int nn = 0; nn < 16; ++nn) {
      const int n = h * 16 + nn;
      const float* wq = sWqk + n * 64;          // LDS
      const float* wk = sWqk + (64 + n) * 64;   // LDS
      const float* wv = g_ipw + (128 + n) * 64; // global (SMEM path)
      float q1 = g_ipb[n], k1 = g_ipb[64 + n], vv = g_ipb[128 + n];
#pragma unroll
      for (int j = 0; j < 64; ++j) {
        q1 += wq[j] * ar[j];
        k1 += wk[j] * ar[j];
        vv += wv[j] * ar[j];
      }
      const float q0n = q0r[n], k0n = k0r[n];
      a01 += q0n * k1;
      a10 += q1 * k0n;
      a11 += q1 * k1;
      const float* ot = opwT + n * 64;          // global (SMEM path)
#pragma unroll
      for (int m = 0; m < 64; ++m) u1[m] += ot[m] * vv;
    }
    s01[h] = a01; s10[h] = a10; s11[h] = a11;
  }

  // softmax per head (scale 1/sqrt(16) = 0.25); s00 from table
  float a00[4], a01c[4], a10c[4], a11c[4];
#pragma unroll
  for (int h = 0; h < 4; ++h) {
    const float t00 = ws[768 + hw * 4 + h] * 0.25f;
    const float t01 = s01[h] * 0.25f;
    const float t10 = s10[h] * 0.25f;
    const float t11 = s11[h] * 0.25f;
    const float mA = fmaxf(t00, t01);
    const float e0 = __expf(t00 - mA), e1 = __expf(t01 - mA);
    const float iA = 1.f / (e0 + e1);
    a00[h] = e0 * iA; a01c[h] = e1 * iA;
    const float mB = fmaxf(t10, t11);
    const float f0 = __expf(t10 - mB), f1 = __expf(t11 - mB);
    const float iB = 1.f / (f0 + f1);
    a10c[h] = f0 * iB; a11c[h] = f1 * iB;
  }

  float pooled[64];
  // token1 first (frees ar): t1 = opb + a10*u0 + a11*u1 + ar ; LN2
  {
    float t1[64];
    float mean = 0.f;
#pragma unroll
    for (int n = 0; n < 64; ++n) {
      const int h = n >> 4;
      const float s = g_opb[n] + a10c[h] * u0r[n] + a11c[h] * u1[n] + ar[n];
      t1[n] = s; mean += s;
    }
    mean *= (1.f / 64.f);
    float var = 0.f;
#pragma unroll
    for (int n = 0; n < 64; ++n) { const float d = t1[n] - mean; var += d * d; }
    var *= (1.f / 64.f);
    const float rstd = rsqrtf(var + 1e-5f);
#pragma unroll
    for (int n = 0; n < 64; ++n)
      pooled[n] = 0.5f * ((t1[n] - mean) * rstd * g_ln2g[n] + g_ln2b[n]);
  }
  // token0: t0 = opb + a00*u0 + a01*u1 + x0 ; LN2
  {
    const float* x0r = g_hwe + hw * 64;
    float t0[64];
    float mean = 0.f;
#pragma unroll
    for (int n = 0; n < 64; ++n) {
      const int h = n >> 4;
      const float s = g_opb[n] + a00[h] * u0r[n] + a01c[h] * u1[n] + x0r[n];
      t0[n] = s; mean += s;
    }
    mean *= (1.f / 64.f);
    float var = 0.f;
#pragma unroll
    for (int n = 0; n < 64; ++n) { const float d = t0[n] - mean; var += d * d; }
    var *= (1.f / 64.f);
    const float rstd = rsqrtf(var + 1e-5f);
#pragma unroll
    for (int n = 0; n < 64; ++n)
      pooled[n] += 0.5f * ((t0[n] - mean) * rstd * g_ln2g[n] + g_ln2b[n]);
  }

  // head: rolled over m, inner unrolled
  float acc = g_b4[0];
#pragma unroll 1
  for (int m = 0; m < 32; ++m) {
    const float* w = g_W3 + m * 64;
    float y = g_b3[m];
#pragma unroll
    for (int j = 0; j < 64; ++j) y += w[j] * pooled[j];
    y = y > 0.f ? y : 0.f;
    acc += y * g_W4[m];
  }
  g_out[i] = acc;
}

extern "C" void kernel_launch(void* const* d_in, const int* in_sizes, int n_in,
                              void* d_out, int out_size, void* d_ws, size_t ws_size,
                              hipStream_t stream) {
  (void)in_sizes; (void)n_in; (void)out_size; (void)ws_size;
  float* ws = (float*)d_ws;

  k_pre<<<1, 256, 0, stream>>>(
      (const float*)d_in[3], (const float*)d_in[10], (const float*)d_in[11],
      (const float*)d_in[12], (const float*)d_in[6], ws);

  k_enc<<<BTOT / 256, 256, 0, stream>>>(
      (const int*)d_in[1], (const int*)d_in[2],
      (const float*)d_in[4], (const float*)d_in[5],
      (const float*)d_in[7],
      (const float*)d_in[8], (const float*)d_in[9],
      ws);

  k_attn<<<BTOT / 256, 256, 0, stream>>>(
      (const int*)d_in[0],
      (const float*)d_in[3],
      (const float*)d_in[10], (const float*)d_in[11],
      (const float*)d_in[13],
      (const float*)d_in[14], (const float*)d_in[15],
      (const float*)d_in[16], (const float*)d_in[17],
      (const float*)d_in[18], (const float*)d_in[19],
      ws, (float*)d_out);
}